// Round 7
// baseline (73.390 us; speedup 1.0000x reference)
//
#include <hip/hip_runtime.h>
#include <hip/hip_bf16.h>
#include <math.h>

namespace {

constexpr int B = 4, S = 2048, D = 1024, H = 64, NH = 16;
constexpr int BS = B * S;                  // 8192 rows
constexpr float SCALE2 = 0.125f * 1.4426950408889634f;  // 1/sqrt(H)*log2(e): exp2 domain

constexpr int AUNITS_PB = 272;             // sum_{J=0..31} ceil((J+1)/2)
constexpr int AUNITS = AUNITS_PB * 4;      // 1088

using f32x4 = __attribute__((ext_vector_type(4))) float;
using short8b = __attribute__((ext_vector_type(8))) short;  // 8 bf16 (4 VGPRs)

__device__ inline ushort f2bf(float f) {
    __hip_bfloat16 h = __float2bfloat16(f);
    return *reinterpret_cast<ushort*>(&h);
}
__device__ inline float bf2f(ushort u) {
    __hip_bfloat16 h = *reinterpret_cast<__hip_bfloat16*>(&u);
    return __bfloat162float(h);
}
// units preceding 64-row group J (chunks of <=2 k-tiles, per batch)
__device__ inline int cum_units(int J) {
    return (J & 1) ? ((J + 1) * (J + 1) / 4) : (J * J / 4 + J / 2);
}

// ---------------------------------------------------------------------------
// prep: [bid<768]  Wt[n][k] bf16 = W{q,k,v}[k][n&63]   (QKV B-operand)
//       [bid>=768] Wpet[e][h] bf16 = sum_t Wproj[t*64+h][e]  (proj B-operand)
// ---------------------------------------------------------------------------
__global__ __launch_bounds__(256) void prep_kernel(const float* __restrict__ Wq,
                                                   const float* __restrict__ Wk,
                                                   const float* __restrict__ Wv,
                                                   const float* __restrict__ Wproj,
                                                   ushort* __restrict__ Wt,
                                                   ushort* __restrict__ Wpet) {
    const int bid = blockIdx.x;
    const int tid = threadIdx.x;
    if (bid < 768) {
        const int idx = bid * 256 + tid;          // 0..196607
        const int n = idx >> 10, k = idx & 1023;
        const float* __restrict__ W = (n < 64) ? Wq : (n < 128) ? Wk : Wv;
        Wt[idx] = f2bf(W[k * 64 + (n & 63)]);
    } else {
        const int idx = (bid - 768) * 256 + tid;  // 0..65535
        const int e = idx & 1023, h = idx >> 10;
        float s = 0.f;
#pragma unroll
        for (int t = 0; t < NH; ++t) s += Wproj[(t * H + h) * D + e];
        Wpet[e * 64 + h] = f2bf(s);
    }
}

// ---------------------------------------------------------------------------
// qkv via MFMA, barrier-free K-loop.
// Block = 512 thr (8 waves: 2M x 4N), M-tile 32 rows, grid 256.
// x tile [32][1024] staged ONCE into swizzled LDS (64 KB); then 16 K-steps
// with A-frags from LDS and B-frags loaded directly from L2-resident Wt.
// ---------------------------------------------------------------------------
__global__ __launch_bounds__(512) void qkv4_kernel(const float* __restrict__ x,
                                                   const ushort* __restrict__ Wt,
                                                   ushort* __restrict__ qb,
                                                   ushort* __restrict__ kb,
                                                   ushort* __restrict__ vb) {
    __shared__ ushort xs[32 * 1024];   // 64 KB
    const int tid = threadIdx.x;
    const int lane = tid & 63;
    const int li = lane & 15, lg = lane >> 4;
    const int wave = tid >> 6;
    const int wm = wave >> 2, wn = wave & 3;   // 2 M-halves x 4 N-groups(48 cols)
    const int row0 = blockIdx.x * 32;

    // ---- stage x once: thread -> row tid>>4, k-base (tid&15)*64 ----
    {
        const int r = tid >> 4, kb0 = (tid & 15) * 64;
        const float* xp = x + (size_t)(row0 + r) * 1024 + kb0;
        char* base = reinterpret_cast<char*>(xs);
#pragma unroll
        for (int i = 0; i < 8; ++i) {
            const float4 f0 = *reinterpret_cast<const float4*>(xp + i * 8);
            const float4 f1 = *reinterpret_cast<const float4*>(xp + i * 8 + 4);
            ushort u[8] = {f2bf(f0.x), f2bf(f0.y), f2bf(f0.z), f2bf(f0.w),
                           f2bf(f1.x), f2bf(f1.y), f2bf(f1.z), f2bf(f1.w)};
            int boff = r * 2048 + (kb0 + i * 8) * 2;
            boff ^= (r & 7) << 4;
            *reinterpret_cast<int4*>(base + boff) = *reinterpret_cast<int4*>(u);
        }
    }

    f32x4 acc[3];
#pragma unroll
    for (int t = 0; t < 3; ++t) acc[t] = (f32x4){0.f, 0.f, 0.f, 0.f};

    __syncthreads();

    const char* xsb = reinterpret_cast<const char*>(xs);
    const ushort* wtbase = Wt + (size_t)(wn * 48) * 1024;
    const int arow = wm * 16 + li;

#pragma unroll 4
    for (int k0 = 0; k0 < 1024; k0 += 64) {
        int aoff = arow * 2048 + k0 * 2 + lg * 16;
        aoff ^= (arow & 7) << 4;
        const short8b a0 = *reinterpret_cast<const short8b*>(xsb + aoff);
        const short8b a1 = *reinterpret_cast<const short8b*>(xsb + (aoff ^ 64));
#pragma unroll
        for (int t = 0; t < 3; ++t) {
            const ushort* bg = wtbase + (size_t)(t * 16 + li) * 1024 + k0 + lg * 8;
            const short8b b0 = *reinterpret_cast<const short8b*>(bg);
            const short8b b1 = *reinterpret_cast<const short8b*>(bg + 32);
            acc[t] = __builtin_amdgcn_mfma_f32_16x16x32_bf16(a0, b0, acc[t], 0, 0, 0);
            acc[t] = __builtin_amdgcn_mfma_f32_16x16x32_bf16(a1, b1, acc[t], 0, 0, 0);
        }
    }

    // epilogue: C col = li (m89 layout); q scaled into exp2 domain
#pragma unroll
    for (int t = 0; t < 3; ++t) {
        const int col = wn * 48 + t * 16 + li;
        const int m = col >> 6, cc = col & 63;
        ushort* __restrict__ dst = (m == 0) ? qb : (m == 1) ? kb : vb;
        const float sc = (m == 0) ? SCALE2 : 1.f;
#pragma unroll
        for (int r = 0; r < 4; ++r) {
            const int gr = row0 + wm * 16 + lg * 4 + r;
            dst[(size_t)gr * 64 + cc] = f2bf(acc[t][r] * sc);
        }
    }
}

// ---------------------------------------------------------------------------
// MFMA causal flash attention, uniform units.
// Unit = (batch b, 64-row q-group J, chunk c of <=2 k-tiles). 272 units/batch,
// grid = 1088 blocks x 256 thr (4 waves; wave owns 16 q-rows).
// K/V tile (64 keys) staged cooperatively by all 256 threads; K swizzled rows,
// V^T via v_perm transpose. Partials (o bf16, m, l) per unit.
// ---------------------------------------------------------------------------
__global__ __launch_bounds__(256) void attn_mfma2_kernel(const ushort* __restrict__ qb,
                                                         const ushort* __restrict__ kb16,
                                                         const ushort* __restrict__ vb16,
                                                         ushort* __restrict__ po,
                                                         float* __restrict__ pm,
                                                         float* __restrict__ pl) {
    __shared__ ushort ksm[64 * 64];
    __shared__ ushort vtm[64 * 64];
    __shared__ ushort plds[4][16 * 72];

    const int tid = threadIdx.x;
    const int lane = tid & 63;
    const int wave = tid >> 6;
    const int li = lane & 15, lg = lane >> 4;
    const int u = blockIdx.x;
    const int b = u & 3;
    const int ub = u >> 2;                 // 0..271

    // decode ub -> (J, c)
    int J = (int)(2.f * sqrtf((float)ub + 0.5f));
    if (J > 31) J = 31;
    while (cum_units(J + 1) <= ub) ++J;
    while (cum_units(J) > ub) --J;
    const int c = ub - cum_units(J);
    const int kt_begin = 2 * c;
    const int kt_end = min(2 * c + 2, J + 1);

    // Q fragments: wave's 16 rows
    const ushort* qg = qb + (size_t)(b * S + J * 64 + wave * 16 + li) * 64 + lg * 8;
    const short8b aq0 = *reinterpret_cast<const short8b*>(qg);
    const short8b aq1 = *reinterpret_cast<const short8b*>(qg + 32);

    f32x4 oacc[4];
#pragma unroll
    for (int t = 0; t < 4; ++t) oacc[t] = (f32x4){0.f, 0.f, 0.f, 0.f};
    float mrow[4] = {-1e30f, -1e30f, -1e30f, -1e30f};
    float lrow[4] = {0.f, 0.f, 0.f, 0.f};

    for (int kt = kt_begin; kt < kt_end; ++kt) {
        __syncthreads();   // previous iter's readers done before overwrite
        // ---- stage K tile (2 chunks/thread) ----
        {
            const ushort* kg = kb16 + (size_t)(b * S + kt * 64) * 64;
#pragma unroll
            for (int it = 0; it < 2; ++it) {
                const int f = tid + it * 256;
                const int key = f >> 3, hd8 = f & 7;
                const int4 val = *reinterpret_cast<const int4*>(kg + key * 64 + hd8 * 8);
                int byteoff = (key << 7) + (hd8 << 4);
                byteoff ^= (key & 7) << 4;
                *reinterpret_cast<int4*>(reinterpret_cast<char*>(ksm) + byteoff) = val;
            }
        }
        // ---- stage V^T tile (1 item/thread) ----
        {
            const ushort* vg = vb16 + (size_t)(b * S + kt * 64) * 64;
            const int kk = tid >> 4;       // key quad
            const int hq = tid & 15;       // h quad
            const uint2 a0 = *reinterpret_cast<const uint2*>(vg + (kk * 4 + 0) * 64 + hq * 4);
            const uint2 a1 = *reinterpret_cast<const uint2*>(vg + (kk * 4 + 1) * 64 + hq * 4);
            const uint2 a2 = *reinterpret_cast<const uint2*>(vg + (kk * 4 + 2) * 64 + hq * 4);
            const uint2 a3 = *reinterpret_cast<const uint2*>(vg + (kk * 4 + 3) * 64 + hq * 4);
#pragma unroll
            for (int i = 0; i < 4; ++i) {
                const uint s0 = (i < 2) ? a0.x : a0.y;
                const uint s1 = (i < 2) ? a1.x : a1.y;
                const uint s2 = (i < 2) ? a2.x : a2.y;
                const uint s3 = (i < 2) ? a3.x : a3.y;
                const uint sel = (i & 1) ? 0x07060302u : 0x05040100u;
                const uint w0 = __builtin_amdgcn_perm(s1, s0, sel);
                const uint w1 = __builtin_amdgcn_perm(s3, s2, sel);
                const int h = hq * 4 + i;
                int byteoff = (h << 7) + (kk << 3);
                byteoff ^= (h & 7) << 4;
                *reinterpret_cast<uint2*>(reinterpret_cast<char*>(vtm) + byteoff) =
                    make_uint2(w0, w1);
            }
        }
        __syncthreads();

        // ---- QK^T ----
        f32x4 accs[4];
#pragma unroll
        for (int t = 0; t < 4; ++t) accs[t] = (f32x4){0.f, 0.f, 0.f, 0.f};
#pragma unroll
        for (int t = 0; t < 4; ++t) {
            const int key = t * 16 + li;
#pragma unroll
            for (int c2 = 0; c2 < 2; ++c2) {
                int byteoff = (key << 7) + (c2 << 6) + (lg << 4);
                byteoff ^= (key & 7) << 4;
                const short8b bk = *reinterpret_cast<const short8b*>(
                    reinterpret_cast<const char*>(ksm) + byteoff);
                accs[t] = __builtin_amdgcn_mfma_f32_16x16x32_bf16(
                    (c2 == 0) ? aq0 : aq1, bk, accs[t], 0, 0, 0);
            }
        }

        // ---- online softmax (exp2 domain) ----
        const bool straddle = (kt == J);
        float sv[4][4];
#pragma unroll
        for (int t = 0; t < 4; ++t) {
            const int kg = kt * 64 + t * 16 + li;
#pragma unroll
            for (int r = 0; r < 4; ++r) {
                const int qrow = J * 64 + wave * 16 + lg * 4 + r;
                sv[t][r] = (straddle && kg > qrow) ? -1e30f : accs[t][r];
            }
        }
        float pvals[4][4];
#pragma unroll
        for (int r = 0; r < 4; ++r) {
            float smax = fmaxf(fmaxf(sv[0][r], sv[1][r]), fmaxf(sv[2][r], sv[3][r]));
#pragma unroll
            for (int off = 1; off < 16; off <<= 1)
                smax = fmaxf(smax, __shfl_xor(smax, off, 64));
            const float mn = fmaxf(mrow[r], smax);
            const float corr = exp2f(mrow[r] - mn);
            mrow[r] = mn;
            float rsum = 0.f;
#pragma unroll
            for (int t = 0; t < 4; ++t) {
                pvals[t][r] = exp2f(sv[t][r] - mn);
                rsum += pvals[t][r];
            }
#pragma unroll
            for (int off = 1; off < 16; off <<= 1)
                rsum += __shfl_xor(rsum, off, 64);
            lrow[r] = lrow[r] * corr + rsum;
#pragma unroll
            for (int t = 0; t < 4; ++t) oacc[t][r] *= corr;
        }

        // ---- P -> LDS (bf16, per-wave buffer) ----
#pragma unroll
        for (int t = 0; t < 4; ++t)
#pragma unroll
            for (int r = 0; r < 4; ++r)
                plds[wave][(lg * 4 + r) * 72 + t * 16 + li] = f2bf(pvals[t][r]);
        __syncthreads();

        // ---- PV ----
        const short8b ap0 = *reinterpret_cast<const short8b*>(
            reinterpret_cast<const char*>(plds[wave]) + li * 144 + (lg << 4));
        const short8b ap1 = *reinterpret_cast<const short8b*>(
            reinterpret_cast<const char*>(plds[wave]) + li * 144 + 64 + (lg << 4));
#pragma unroll
        for (int t = 0; t < 4; ++t) {
            const int h = t * 16 + li;
#pragma unroll
            for (int c2 = 0; c2 < 2; ++c2) {
                int byteoff = (h << 7) + (c2 << 6) + (lg << 4);
                byteoff ^= (h & 7) << 4;
                const short8b bv = *reinterpret_cast<const short8b*>(
                    reinterpret_cast<const char*>(vtm) + byteoff);
                oacc[t] = __builtin_amdgcn_mfma_f32_16x16x32_bf16(
                    (c2 == 0) ? ap0 : ap1, bv, oacc[t], 0, 0, 0);
            }
        }
    }

    // ---- write partials ----
    if (li == 0) {
#pragma unroll
        for (int r = 0; r < 4; ++r) {
            pm[u * 64 + wave * 16 + lg * 4 + r] = mrow[r];
            pl[u * 64 + wave * 16 + lg * 4 + r] = lrow[r];
        }
    }
#pragma unroll
    for (int t = 0; t < 4; ++t)
#pragma unroll
        for (int r = 0; r < 4; ++r)
            po[(size_t)u * 4096 + (wave * 16 + lg * 4 + r) * 64 + t * 16 + li] =
                f2bf(oacc[t][r]);
}

// ---------------------------------------------------------------------------
// Fused combine + projection.  Block (256 thr) per 16-row q-tile (512 blocks).
// Phase 1: merge nc = ceil((J+1)/2) partials -> bf16 ctx tile in swizzled LDS.
// Phase 2: out[16][1024] = ctx @ Wpet + bias via MFMA; wave w -> cols w*256..
// ---------------------------------------------------------------------------
__global__ __launch_bounds__(256) void proj_fused_kernel(const ushort* __restrict__ po,
                                                         const float* __restrict__ pm,
                                                         const float* __restrict__ pl,
                                                         const ushort* __restrict__ Wpet,
                                                         const float* __restrict__ bias,
                                                         float* __restrict__ out) {
    __shared__ ushort ctxs[16 * 64];
    const int tid = threadIdx.x;
    const int bid = blockIdx.x;            // 0..511
    const int b = bid >> 7, j = bid & 127;
    const int J = j >> 2;
    const int nc = (J + 2) >> 1;
    const int cumJ = cum_units(J);

    // ---- phase 1: combine partials; thread -> (row qr, 4 h's) ----
    {
        const int qr = tid >> 4, hq = tid & 15;
        const int riu = (j & 3) * 16 + qr;     // row within 64-row unit
        float M = -1e30f;
        for (int cc = 0; cc < nc; ++cc) {
            const int uu = (cumJ + cc) * 4 + b;
            M = fmaxf(M, pm[uu * 64 + riu]);
        }
        float denom = 0.f;
        float acc[4] = {0.f, 0.f, 0.f, 0.f};
        for (int cc = 0; cc < nc; ++cc) {
            const int uu = (cumJ + cc) * 4 + b;
            const float sc = exp2f(pm[uu * 64 + riu] - M);
            denom += pl[uu * 64 + riu] * sc;
            const ushort* pp = po + (size_t)uu * 4096 + riu * 64 + hq * 4;
            acc[0] += bf2f(pp[0]) * sc;
            acc[1] += bf2f(pp[1]) * sc;
            acc[2] += bf2f(pp[2]) * sc;
            acc[3] += bf2f(pp[3]) * sc;
        }
        const float inv = 1.f / denom;
        ushort uu4[4] = {f2bf(acc[0] * inv), f2bf(acc[1] * inv),
                         f2bf(acc[2] * inv), f2bf(acc[3] * inv)};
        int boff = qr * 128 + hq * 8;
        boff ^= (qr & 7) << 4;
        *reinterpret_cast<uint2*>(reinterpret_cast<char*>(ctxs) + boff) =
            *reinterpret_cast<uint2*>(uu4);
    }
    __syncthreads();

    // ---- phase 2: MFMA projection ----
    const int lane = tid & 63;
    const int li = lane & 15, lg = lane >> 4;
    const int wave = tid >> 6;
    const int col0 = wave * 256;
    const int row0 = bid * 16;

    int aoff = li * 128 + lg * 16;
    aoff ^= (li & 7) << 4;
    const short8b a0 = *reinterpret_cast<const short8b*>(
        reinterpret_cast<const char*>(ctxs) + aoff);
    const short8b a1 = *reinterpret_cast<const short8b*>(
        reinterpret_cast<const char*>(ctxs) + (aoff ^ 64));

#pragma unroll
    for (int t = 0; t < 16; ++t) {
        const int col = col0 + t * 16 + li;
        const ushort* bg = Wpet + (size_t)col * 64 + lg * 8;
        const short8b b0 = *reinterpret_cast<const short8b*>(bg);
        const short8b b1 = *reinterpret_cast<const short8b*>(bg + 32);
        f32x4 acc = (f32x4){0.f, 0.f, 0.f, 0.f};
        acc = __builtin_amdgcn_mfma_f32_16x16x32_bf16(a0, b0, acc, 0, 0, 0);
        acc = __builtin_amdgcn_mfma_f32_16x16x32_bf16(a1, b1, acc, 0, 0, 0);
        const float bb = bias[col];
#pragma unroll
        for (int r = 0; r < 4; ++r)
            out[(size_t)(row0 + lg * 4 + r) * 1024 + col] = acc[r] + bb;
    }
}

}  // namespace

extern "C" void kernel_launch(void* const* d_in, const int* in_sizes, int n_in,
                              void* d_out, int out_size, void* d_ws, size_t ws_size,
                              hipStream_t stream) {
    const float* x     = (const float*)d_in[0];
    const float* Wq    = (const float*)d_in[1];
    const float* Wk    = (const float*)d_in[2];
    const float* Wv    = (const float*)d_in[3];
    const float* Wproj = (const float*)d_in[4];
    const float* bproj = (const float*)d_in[5];
    float* out = (float*)d_out;

    const size_t BSH = (size_t)BS * H;          // 524288
    // ws layout: qb 1MB | kb 1MB | vb 1MB | Wt 384KB | Wpet 128KB
    //            | po 8.9MB | pm 278KB | pl 278KB   (~12.9 MB)
    ushort* qb   = (ushort*)d_ws;
    ushort* kb   = qb + BSH;
    ushort* vb   = kb + BSH;
    ushort* Wt   = vb + BSH;                    // 192*1024
    ushort* Wpet = Wt + 192 * 1024;             // 1024*64
    ushort* po   = Wpet + 65536;                // AUNITS*4096
    float*  pm   = (float*)(po + (size_t)AUNITS * 4096);
    float*  pl   = pm + AUNITS * 64;

    hipLaunchKernelGGL(prep_kernel, dim3(1024), dim3(256), 0, stream, Wq, Wk, Wv, Wproj, Wt, Wpet);
    hipLaunchKernelGGL(qkv4_kernel, dim3(BS / 32), dim3(512), 0, stream, x, Wt, qb, kb, vb);
    hipLaunchKernelGGL(attn_mfma2_kernel, dim3(AUNITS), dim3(256), 0, stream,
                       qb, kb, vb, po, pm, pl);
    hipLaunchKernelGGL(proj_fused_kernel, dim3(512), dim3(256), 0, stream,
                       po, pm, pl, Wpet, bproj, out);
}